// Round 1
// 516.712 us; speedup vs baseline: 1.0103x; 1.0103x over previous
//
#include <hip/hip_runtime.h>

// Problem: B=8, N=1024, D=1024, H=16, HD=64, FF=4096. Tokens M = 8192.
// Inputs f32, OUTPUT f32. Internals bf16, f32 accumulation.
// Round 8: XCD-aware block swizzle on ffn2 GEMM (M=8192,N=1024,K=4096).
// rocprof showed ffn2 FETCH=274MB vs 88MB compulsory (A panels re-fetched
// ~4x because the 8 n-tile blocks sharing an A panel round-robin onto 8
// different XCD L2s). Bijective blocked remap co-locates all n-tiles of an
// 8-m-tile chunk on one XCD. swz=1 only for ffn2; other GEMMs are
// L3-resident (swizzle known neutral/-2% there). Rest unchanged from R7.

typedef unsigned short ushort_t;
typedef __bf16 bf16x8 __attribute__((ext_vector_type(8)));
typedef float f32x4 __attribute__((ext_vector_type(4)));
typedef unsigned short u16x8 __attribute__((ext_vector_type(8)));

__device__ __forceinline__ void async_ld16(const void* g, void* l) {
  // global -> LDS direct, 16B per lane. LDS dst is wave-uniform base; HW
  // writes base + lane*16.
  __builtin_amdgcn_global_load_lds(
      (void __attribute__((address_space(1)))*)const_cast<void*>(g),
      (void __attribute__((address_space(3)))*)l, 16, 0, 0);
}

__device__ __forceinline__ float bf2f(ushort_t h) {
  union { unsigned int u; float f; } v;
  v.u = ((unsigned int)h) << 16;
  return v.f;
}
__device__ __forceinline__ ushort_t f2bf(float f) {
  union { float f; unsigned int u; } v;
  v.f = f;
  unsigned int r = v.u + 0x7FFFu + ((v.u >> 16) & 1u);  // RNE
  return (ushort_t)(r >> 16);
}
// tanh-form GELU (~3e-4 dev from exact erf; 0.078 threshold headroom)
__device__ __forceinline__ float gelu_f(float x) {
  float y = 0.7978845608028654f * (x + 0.044715f * x * x * x);
  float e = __expf(2.0f * y);
  float t = 1.0f - 2.0f / (e + 1.0f);
  return 0.5f * x * (1.0f + t);
}

// ---------------- f32 -> bf16 weight conversion (8 elems/thread) ------------
__global__ void __launch_bounds__(256) cvt_f32_bf16(const float* __restrict__ src,
                                                    ushort_t* __restrict__ dst, int n) {
  int i = (blockIdx.x * 256 + threadIdx.x) * 8;
  if (i >= n) return;
  float4 a = *(const float4*)(src + i);
  float4 b = *(const float4*)(src + i + 4);
  u16x8 o;
  o[0] = f2bf(a.x); o[1] = f2bf(a.y); o[2] = f2bf(a.z); o[3] = f2bf(a.w);
  o[4] = f2bf(b.x); o[5] = f2bf(b.y); o[6] = f2bf(b.z); o[7] = f2bf(b.w);
  *(u16x8*)(dst + i) = o;
}

// ---------------- LayerNorm (f32 in, bf16 out): 1 wave per token ------------
__global__ void __launch_bounds__(256) ln_f32(const float* __restrict__ X,
                                              const float* __restrict__ G,
                                              const float* __restrict__ Bb,
                                              ushort_t* __restrict__ Y) {
  int tok = blockIdx.x * 4 + (threadIdx.x >> 6);
  int lane = threadIdx.x & 63;
  const float* xr = X + (size_t)tok * 1024 + lane * 16;
  float v[16];
#pragma unroll
  for (int c = 0; c < 4; c++) {
    float4 a = *(const float4*)(xr + c * 4);
    v[c * 4 + 0] = a.x; v[c * 4 + 1] = a.y; v[c * 4 + 2] = a.z; v[c * 4 + 3] = a.w;
  }
  float s = 0.f, ss = 0.f;
#pragma unroll
  for (int j = 0; j < 16; j++) { s += v[j]; ss += v[j] * v[j]; }
#pragma unroll
  for (int off = 32; off >= 1; off >>= 1) {
    s += __shfl_xor(s, off);
    ss += __shfl_xor(ss, off);
  }
  float mu = s * (1.f / 1024.f);
  float var = ss * (1.f / 1024.f) - mu * mu;
  float rs = rsqrtf(var + 1e-5f);
  u16x8 o0, o1;
#pragma unroll
  for (int c = 0; c < 4; c++) {
    float4 g = *(const float4*)(G + lane * 16 + c * 4);
    float4 bb = *(const float4*)(Bb + lane * 16 + c * 4);
    ushort_t* op = (c < 2) ? (ushort_t*)&o0 : (ushort_t*)&o1;
    int base = (c & 1) * 4;
    op[base + 0] = f2bf((v[c * 4 + 0] - mu) * rs * g.x + bb.x);
    op[base + 1] = f2bf((v[c * 4 + 1] - mu) * rs * g.y + bb.y);
    op[base + 2] = f2bf((v[c * 4 + 2] - mu) * rs * g.z + bb.z);
    op[base + 3] = f2bf((v[c * 4 + 3] - mu) * rs * g.w + bb.w);
  }
  ushort_t* yr = Y + (size_t)tok * 1024 + lane * 16;
  *(u16x8*)yr = o0;
  *(u16x8*)(yr + 8) = o1;
}

// ---------------- LayerNorm (bf16 in, bf16 out): 1 wave per token -----------
__global__ void __launch_bounds__(256) ln_bf16(const ushort_t* __restrict__ X,
                                               const float* __restrict__ G,
                                               const float* __restrict__ Bb,
                                               ushort_t* __restrict__ Y) {
  int tok = blockIdx.x * 4 + (threadIdx.x >> 6);
  int lane = threadIdx.x & 63;
  const ushort_t* xr = X + (size_t)tok * 1024 + lane * 16;
  u16x8 x0 = *(const u16x8*)xr;
  u16x8 x1 = *(const u16x8*)(xr + 8);
  float v[16];
  float s = 0.f, ss = 0.f;
#pragma unroll
  for (int j = 0; j < 8; j++) { v[j] = bf2f(x0[j]); v[8 + j] = bf2f(x1[j]); }
#pragma unroll
  for (int j = 0; j < 16; j++) { s += v[j]; ss += v[j] * v[j]; }
#pragma unroll
  for (int off = 32; off >= 1; off >>= 1) {
    s += __shfl_xor(s, off);
    ss += __shfl_xor(ss, off);
  }
  float mu = s * (1.f / 1024.f);
  float var = ss * (1.f / 1024.f) - mu * mu;
  float rs = rsqrtf(var + 1e-5f);
  u16x8 o0, o1;
#pragma unroll
  for (int c = 0; c < 4; c++) {
    float4 g = *(const float4*)(G + lane * 16 + c * 4);
    float4 bb = *(const float4*)(Bb + lane * 16 + c * 4);
    ushort_t* op = (c < 2) ? (ushort_t*)&o0 : (ushort_t*)&o1;
    int base = (c & 1) * 4;
    op[base + 0] = f2bf((v[c * 4 + 0] - mu) * rs * g.x + bb.x);
    op[base + 1] = f2bf((v[c * 4 + 1] - mu) * rs * g.y + bb.y);
    op[base + 2] = f2bf((v[c * 4 + 2] - mu) * rs * g.z + bb.z);
    op[base + 3] = f2bf((v[c * 4 + 3] - mu) * rs * g.w + bb.w);
  }
  ushort_t* yr = Y + (size_t)tok * 1024 + lane * 16;
  *(u16x8*)yr = o0;
  *(u16x8*)(yr + 8) = o1;
}

// ---------------- GEMM: C[M,N] = act(A[M,K] @ B[N,K]^T + bias) (+Res) -------
// 128x128 tile, BK=64, 4 waves 2x2, 4x4 frags of 16x16x32 bf16 MFMA,
// global_load_lds width=16 staging, K/64 K-iters.
// Tiles: row-major [128][64], granule g (8 el) of row r at slot g^(r&7)
//   staging source col = ((t&7)^((t>>3)&7))*8; frag read slot (c*4+quad)^(l16&7).
// __launch_bounds__(256,4): cap 128 unified regs -> 4 blocks/CU.
// Epilogue repack buffer aliases sA (safe after final K-loop barrier).
// swz=1: bijective XCD-blocked remap (requires grid count % 8 == 0 and
// gridDim.y % 8 == 0; true at all call sites). XCD x (= lid%8, HW
// round-robin) owns m-tiles [x*ny/8, (x+1)*ny/8) x all n-tiles, so the
// blocks sharing an A panel hit the same per-XCD L2.
__global__ void __launch_bounds__(256, 4) gemm_bt(const ushort_t* __restrict__ A,
                                                  const ushort_t* __restrict__ Bw,
                                                  const float* __restrict__ bias,
                                                  const float* __restrict__ ResF,
                                                  const ushort_t* __restrict__ ResB,
                                                  ushort_t* __restrict__ Cb,
                                                  float* __restrict__ Cf,
                                                  int M, int N, int K, int act, int swz) {
  __shared__ __align__(16) ushort_t sAB[2 * 128 * 64];  // sA | sB, 32 KB
  ushort_t* sA = sAB;
  ushort_t* sB = sAB + 8192;
  int t = threadIdx.x;
  int wave = t >> 6, lane = t & 63;
  int quad = lane >> 4, l16 = lane & 15;
  int wm = (wave & 1) * 64, wn = (wave >> 1) * 64;

  int bx = blockIdx.x, by = blockIdx.y;
  if (swz) {
    int lid = by * gridDim.x + bx;
    int xcd = lid & 7, slot = lid >> 3;
    int mchunk = gridDim.y >> 3;           // m-tiles per XCD
    by = xcd * mchunk + slot / gridDim.x;
    bx = slot % gridDim.x;
  }
  int m0 = by * 128, n0 = bx * 128;

  f32x4 zero = {0.f, 0.f, 0.f, 0.f};
  f32x4 acc[4][4];
#pragma unroll
  for (int i = 0; i < 4; i++)
#pragma unroll
    for (int j = 0; j < 4; j++) acc[i][j] = zero;

  // staging: pass p, thread t covers LDS cell p*256+t -> row p*32+(t>>3),
  // slot t&7; source granule = slot ^ (row&7) = (t&7)^((t>>3)&7)
  int srow = t >> 3;
  int scol = ((t & 7) ^ ((t >> 3) & 7)) * 8;
  const ushort_t* gA = A + (size_t)(m0 + srow) * K + scol;
  const ushort_t* gB = Bw + (size_t)(n0 + srow) * K + scol;
  // frag read column offsets (elements), two k-chunks
  int colA0 = ((quad ^ (l16 & 7)) * 8);
  int colA1 = (((4 + quad) ^ (l16 & 7)) * 8);

  for (int k0 = 0; k0 < K; k0 += 64) {
#pragma unroll
    for (int p = 0; p < 4; p++) {
      async_ld16(gA + (size_t)p * 32 * K + k0, sA + p * 2048 + wave * 512);
      async_ld16(gB + (size_t)p * 32 * K + k0, sB + p * 2048 + wave * 512);
    }
    __syncthreads();
#pragma unroll
    for (int c = 0; c < 2; c++) {
      int col = c ? colA1 : colA0;
      bf16x8 af[4], bfr[4];
#pragma unroll
      for (int i = 0; i < 4; i++) {
        af[i]  = *(const bf16x8*)(sA + (wm + i * 16 + l16) * 64 + col);
        bfr[i] = *(const bf16x8*)(sB + (wn + i * 16 + l16) * 64 + col);
      }
#pragma unroll
      for (int mi = 0; mi < 4; mi++)
#pragma unroll
        for (int ni = 0; ni < 4; ni++)
          acc[mi][ni] = __builtin_amdgcn_mfma_f32_16x16x32_bf16(af[mi], bfr[ni], acc[mi][ni], 0, 0, 0);
    }
    __syncthreads();
  }

  // epilogue: C/D layout row = quad*4+r, col = l16 (m89/m91-verified)
  float bv[4];
#pragma unroll
  for (int ni = 0; ni < 4; ni++) bv[ni] = bias[n0 + wn + ni * 16 + l16];

  if (Cf) {
    // f32 output path (ffn2): scalar dword stores, 64B/quad coalesced
#pragma unroll
    for (int mi = 0; mi < 4; mi++) {
      int row = m0 + wm + mi * 16 + quad * 4;
#pragma unroll
      for (int ni = 0; ni < 4; ni++) {
        int col = n0 + wn + ni * 16 + l16;
#pragma unroll
        for (int r = 0; r < 4; r++) {
          size_t idx = (size_t)(row + r) * N + col;
          float vv = acc[mi][ni][r] + bv[ni];
          if (act) vv = gelu_f(vv);
          if (ResB) vv += bf2f(ResB[idx]);
          Cf[idx] = vv;
        }
      }
    }
  } else {
    // bf16 output path: per-wave LDS repack (aliases sA; all K-loop reads
    // completed at final barrier) -> 16B/lane stores
    ushort_t* eb = sAB + wave * (16 * 72);
    int lr = lane >> 2, lc = (lane & 3) * 8;
#pragma unroll
    for (int mi = 0; mi < 4; mi++) {
      int row = m0 + wm + mi * 16;
#pragma unroll
      for (int ni = 0; ni < 4; ni++)
#pragma unroll
        for (int r = 0; r < 4; r++) {
          float vv = acc[mi][ni][r] + bv[ni];
          if (act) vv = gelu_f(vv);
          eb[(quad * 4 + r) * 72 + ni * 16 + l16] = f2bf(vv);
        }
      // same-wave ds write->read (in-order); coalesced u16x8 global stores
#pragma unroll
      for (int hc = 0; hc < 64; hc += 32) {
        u16x8 o = *(const u16x8*)(eb + lr * 72 + hc + lc);
        size_t gidx = (size_t)(row + lr) * N + n0 + wn + hc + lc;
        if (ResF) {
          float4 ra = *(const float4*)(ResF + gidx);
          float4 rb = *(const float4*)(ResF + gidx + 4);
          u16x8 o2;
          o2[0] = f2bf(bf2f(o[0]) + ra.x); o2[1] = f2bf(bf2f(o[1]) + ra.y);
          o2[2] = f2bf(bf2f(o[2]) + ra.z); o2[3] = f2bf(bf2f(o[3]) + ra.w);
          o2[4] = f2bf(bf2f(o[4]) + rb.x); o2[5] = f2bf(bf2f(o[5]) + rb.y);
          o2[6] = f2bf(bf2f(o[6]) + rb.z); o2[7] = f2bf(bf2f(o[7]) + rb.w);
          *(u16x8*)(Cb + gidx) = o2;
        } else {
          *(u16x8*)(Cb + gidx) = o;
        }
      }
    }
  }
}

// ---------------- V transpose: qkv V-part [token, 64] -> Vt[b,h,64,1024] ----
__global__ void __launch_bounds__(256) vtrans(const ushort_t* __restrict__ qkv,
                                              ushort_t* __restrict__ Vt) {
  __shared__ ushort_t tile[64][72];
  int t = threadIdx.x;
  int bh = blockIdx.y;
  int b = bh >> 4, h = bh & 15;
  int n0 = blockIdx.x * 64;
  int r = t >> 3;
  int c8 = (t & 7) * 8;
  const ushort_t* src = qkv + ((size_t)(b * 1024 + n0)) * 3072 + 2048 + h * 64;
#pragma unroll
  for (int rr = r; rr < 64; rr += 32) {
    u16x8 d = *(const u16x8*)(src + (size_t)rr * 3072 + c8);
#pragma unroll
    for (int j = 0; j < 8; j++) tile[rr][c8 + j] = d[j];
  }
  __syncthreads();
#pragma unroll
  for (int hh = r; hh < 64; hh += 32) {
    u16x8 o;
#pragma unroll
    for (int j = 0; j < 8; j++) o[j] = tile[c8 + j][hh];
    *(u16x8*)(Vt + ((size_t)bh * 64 + hh) * 1024 + n0 + c8) = o;
  }
}

// ---------------- Flash attention, S^T formulation (unchanged from R5) ------
__global__ void __launch_bounds__(256) attn_kernel(const ushort_t* __restrict__ qkv,
                                                   const ushort_t* __restrict__ Vt,
                                                   ushort_t* __restrict__ ctx) {
  __shared__ __align__(16) ushort_t sK[128 * 64];
  __shared__ __align__(16) ushort_t sV[64 * 128];
  __shared__ __align__(16) ushort_t sP[4 * 16 * 144];
  int t = threadIdx.x, wave = t >> 6, lane = t & 63;
  int quad = lane >> 4, l16 = lane & 15;
  int bh = blockIdx.y, b = bh >> 4, h = bh & 15;
  int q0 = blockIdx.x * 64 + wave * 16;
  size_t tokbase = (size_t)b * 1024;

  const ushort_t* qrow = qkv + (tokbase + q0 + l16) * 3072 + h * 64;
  bf16x8 qf0 = *(const bf16x8*)(qrow + quad * 8);
  bf16x8 qf1 = *(const bf16x8*)(qrow + 32 + quad * 8);

  f32x4 zero = {0.f, 0.f, 0.f, 0.f};
  f32x4 O[4];
#pragma unroll
  for (int i = 0; i < 4; i++) O[i] = zero;
  float m = -3.0e38f, l = 0.f;

  int kvlK = wave * 32 + (lane >> 3);
  int hdKx = lane & 7;
  ushort_t* pw = sP + wave * (16 * 144);

  for (int kv0 = 0; kv0 < 1024; kv0 += 128) {
#pragma unroll
    for (int j = 0; j < 4; j++) {
      int kvl = kvlK + j * 8;
      int hd = (hdKx ^ (kvl & 7)) * 8;
      async_ld16(qkv + (tokbase + kv0 + kvl) * 3072 + 1024 + h * 64 + hd,
                 sK + wave * 2048 + j * 512);
      int hdv = wave * 16 + j * 4 + (lane >> 4);
      int kvloc = ((lane & 15) ^ (hdv & 15)) * 8;
      async_ld16(Vt + ((size_t)bh * 64 + hdv) * 1024 + kv0 + kvloc,
                 sV + wave * 2048 + j * 512);
    }
    __syncthreads();

    f32x4 st[8];
#pragma unroll
    for (int s = 0; s < 8; s++) {
      bf16x8 kf0 = *(const bf16x8*)(sK + (s * 16 + l16) * 64 + ((quad ^ (l16 & 7)) * 8));
      bf16x8 kf1 = *(const bf16x8*)(sK + (s * 16 + l16) * 64 + (((4 + quad) ^ (l16 & 7)) * 8));
      st[s] = __builtin_amdgcn_mfma_f32_16x16x32_bf16(kf0, qf0, zero, 0, 0, 0);
      st[s] = __builtin_amdgcn_mfma_f32_16x16x32_bf16(kf1, qf1, st[s], 0, 0, 0);
    }
    f32x4 mx4 = st[0];
#pragma unroll
    for (int s = 1; s < 8; s++)
#pragma unroll
      for (int r = 0; r < 4; r++) mx4[r] = fmaxf(mx4[r], st[s][r]);
    float mx = fmaxf(fmaxf(mx4[0], mx4[1]), fmaxf(mx4[2], mx4[3]));
    mx = fmaxf(mx, __shfl_xor(mx, 16));
    mx = fmaxf(mx, __shfl_xor(mx, 32));
    float mnew = fmaxf(m, mx * 0.125f);
    float alpha = __expf(m - mnew);
    m = mnew;
    float rs = 0.f;
#pragma unroll
    for (int s = 0; s < 8; s++)
#pragma unroll
      for (int r = 0; r < 4; r++) {
        st[s][r] = __expf(fmaf(st[s][r], 0.125f, -m));
        rs += st[s][r];
      }
    rs += __shfl_xor(rs, 16);
    rs += __shfl_xor(rs, 32);
    l = l * alpha + rs;
#pragma unroll
    for (int s = 0; s < 8; s++) {
      uint2 pk;
      pk.x = __builtin_amdgcn_perm(__float_as_uint(st[s][1]), __float_as_uint(st[s][0]), 0x07060302u);
      pk.y = __builtin_amdgcn_perm(__float_as_uint(st[s][3]), __float_as_uint(st[s][2]), 0x07060302u);
      *(uint2*)(pw + l16 * 144 + s * 16 + quad * 4) = pk;
    }
#pragma unroll
    for (int ti = 0; ti < 4; ti++)
#pragma unroll
      for (int r = 0; r < 4; r++) O[ti][r] *= alpha;
#pragma unroll
    for (int c = 0; c < 4; c++) {
      bf16x8 pf = *(const bf16x8*)(pw + l16 * 144 + c * 32 + quad * 8);
#pragma unroll
      for (int ti = 0; ti < 4; ti++) {
        bf16x8 vf = *(const bf16x8*)(sV + (ti * 16 + l16) * 128 + (((c * 4 + quad) ^ l16) * 8));
        O[ti] = __builtin_amdgcn_mfma_f32_16x16x32_bf16(vf, pf, O[ti], 0, 0, 0);
      }
    }
    __syncthreads();
  }
  float inv = 1.0f / l;
  ushort_t* cb = ctx + (tokbase + q0 + l16) * 1024 + h * 64;
#pragma unroll
  for (int ti = 0; ti < 4; ti++) {
    uint2 pk;
    pk.x = (unsigned int)f2bf(O[ti][0] * inv) | ((unsigned int)f2bf(O[ti][1] * inv) << 16);
    pk.y = (unsigned int)f2bf(O[ti][2] * inv) | ((unsigned int)f2bf(O[ti][3] * inv) << 16);
    *(uint2*)(cb + ti * 16 + quad * 4) = pk;
  }
}

extern "C" void kernel_launch(void* const* d_in, const int* in_sizes, int n_in,
                              void* d_out, int out_size, void* d_ws, size_t ws_size,
                              hipStream_t stream) {
  (void)in_sizes; (void)n_in; (void)out_size; (void)ws_size;
  const float* x     = (const float*)d_in[0];
  const float* ln1g  = (const float*)d_in[1];
  const float* ln1b  = (const float*)d_in[2];
  const float* ln2g  = (const float*)d_in[3];
  const float* ln2b  = (const float*)d_in[4];
  const float* Wqkv  = (const float*)d_in[5];
  const float* bqkv  = (const float*)d_in[6];
  const float* Wproj = (const float*)d_in[7];
  const float* bproj = (const float*)d_in[8];
  const float* W1    = (const float*)d_in[9];
  const float* b1    = (const float*)d_in[10];
  const float* W2    = (const float*)d_in[11];
  const float* b2    = (const float*)d_in[12];
  float* out = (float*)d_out;
  char* ws = (char*)d_ws;
  const size_t MB = 1u << 20;
  ushort_t* Wqkv_b  = (ushort_t*)(ws + 0);
  ushort_t* Wproj_b = (ushort_t*)(ws + 6 * MB);
  ushort_t* h1      = (ushort_t*)(ws + 8 * MB);
  ushort_t* qkv     = (ushort_t*)(ws + 24 * MB);
  ushort_t* Vt      = (ushort_t*)(ws + 72 * MB);
  ushort_t* ctx     = (ushort_t*)(ws + 8 * MB);
  ushort_t* out1    = (ushort_t*)(ws + 24 * MB);
  ushort_t* W1_b    = (ushort_t*)(ws + 0);
  ushort_t* h2      = (ushort_t*)(ws + 8 * MB);
  ushort_t* ff1     = (ushort_t*)(ws + 40 * MB);
  ushort_t* W2_b    = (ushort_t*)(ws + 0);

  cvt_f32_bf16<<<1536, 256, 0, stream>>>(Wqkv, Wqkv_b, 3 * 1024 * 1024);
  cvt_f32_bf16<<<512, 256, 0, stream>>>(Wproj, Wproj_b, 1024 * 1024);
  ln_f32<<<2048, 256, 0, stream>>>(x, ln1g, ln1b, h1);
  gemm_bt<<<dim3(24, 64), 256, 0, stream>>>(h1, Wqkv_b, bqkv, nullptr, nullptr, qkv, nullptr, 8192, 3072, 1024, 0, 0);
  vtrans<<<dim3(16, 128), 256, 0, stream>>>(qkv, Vt);
  attn_kernel<<<dim3(16, 128), 256, 0, stream>>>(qkv, Vt, ctx);
  gemm_bt<<<dim3(8, 64), 256, 0, stream>>>(ctx, Wproj_b, bproj, x, nullptr, out1, nullptr, 8192, 1024, 1024, 0, 0);
  cvt_f32_bf16<<<2048, 256, 0, stream>>>(W1, W1_b, 4 * 1024 * 1024);
  ln_bf16<<<2048, 256, 0, stream>>>(out1, ln2g, ln2b, h2);
  gemm_bt<<<dim3(32, 64), 256, 0, stream>>>(h2, W1_b, b1, nullptr, nullptr, ff1, nullptr, 8192, 4096, 1024, 1, 0);
  cvt_f32_bf16<<<2048, 256, 0, stream>>>(W2, W2_b, 4 * 1024 * 1024);
  gemm_bt<<<dim3(8, 64), 256, 0, stream>>>(ff1, W2_b, b2, nullptr, out1, nullptr, out, 8192, 1024, 4096, 1, 1);
}

// Round 2
// 506.739 us; speedup vs baseline: 1.0302x; 1.0197x over previous
//
#include <hip/hip_runtime.h>

// Problem: B=8, N=1024, D=1024, H=16, HD=64, FF=4096. Tokens M = 8192.
// Inputs f32, OUTPUT f32. Internals bf16, f32 accumulation.
// Round 9: BK=128 for the grid-limited GEMMs (proj, ffn2: grid 512 blocks =
// 2 blocks/CU, so 64KB LDS costs no occupancy). Halves the per-K-step
// vmcnt(0) barrier drains (ffn2 64->32 iters) which R8 showed are the
// bottleneck (FETCH dropped 3.7x but dur only -6%; MfmaUtil stuck at 29%).
// gemm_bt is now template<int BK>; 16-granule XOR swizzle for BK=128.
// qkv/ffn1 keep BK=64 @ 4 blocks/CU. ffn2 keeps XCD swizzle from R8.

typedef unsigned short ushort_t;
typedef __bf16 bf16x8 __attribute__((ext_vector_type(8)));
typedef float f32x4 __attribute__((ext_vector_type(4)));
typedef unsigned short u16x8 __attribute__((ext_vector_type(8)));

__device__ __forceinline__ void async_ld16(const void* g, void* l) {
  // global -> LDS direct, 16B per lane. LDS dst is wave-uniform base; HW
  // writes base + lane*16.
  __builtin_amdgcn_global_load_lds(
      (void __attribute__((address_space(1)))*)const_cast<void*>(g),
      (void __attribute__((address_space(3)))*)l, 16, 0, 0);
}

__device__ __forceinline__ float bf2f(ushort_t h) {
  union { unsigned int u; float f; } v;
  v.u = ((unsigned int)h) << 16;
  return v.f;
}
__device__ __forceinline__ ushort_t f2bf(float f) {
  union { float f; unsigned int u; } v;
  v.f = f;
  unsigned int r = v.u + 0x7FFFu + ((v.u >> 16) & 1u);  // RNE
  return (ushort_t)(r >> 16);
}
// tanh-form GELU (~3e-4 dev from exact erf; 0.078 threshold headroom)
__device__ __forceinline__ float gelu_f(float x) {
  float y = 0.7978845608028654f * (x + 0.044715f * x * x * x);
  float e = __expf(2.0f * y);
  float t = 1.0f - 2.0f / (e + 1.0f);
  return 0.5f * x * (1.0f + t);
}

// ---------------- f32 -> bf16 weight conversion (8 elems/thread) ------------
__global__ void __launch_bounds__(256) cvt_f32_bf16(const float* __restrict__ src,
                                                    ushort_t* __restrict__ dst, int n) {
  int i = (blockIdx.x * 256 + threadIdx.x) * 8;
  if (i >= n) return;
  float4 a = *(const float4*)(src + i);
  float4 b = *(const float4*)(src + i + 4);
  u16x8 o;
  o[0] = f2bf(a.x); o[1] = f2bf(a.y); o[2] = f2bf(a.z); o[3] = f2bf(a.w);
  o[4] = f2bf(b.x); o[5] = f2bf(b.y); o[6] = f2bf(b.z); o[7] = f2bf(b.w);
  *(u16x8*)(dst + i) = o;
}

// ---------------- LayerNorm (f32 in, bf16 out): 1 wave per token ------------
__global__ void __launch_bounds__(256) ln_f32(const float* __restrict__ X,
                                              const float* __restrict__ G,
                                              const float* __restrict__ Bb,
                                              ushort_t* __restrict__ Y) {
  int tok = blockIdx.x * 4 + (threadIdx.x >> 6);
  int lane = threadIdx.x & 63;
  const float* xr = X + (size_t)tok * 1024 + lane * 16;
  float v[16];
#pragma unroll
  for (int c = 0; c < 4; c++) {
    float4 a = *(const float4*)(xr + c * 4);
    v[c * 4 + 0] = a.x; v[c * 4 + 1] = a.y; v[c * 4 + 2] = a.z; v[c * 4 + 3] = a.w;
  }
  float s = 0.f, ss = 0.f;
#pragma unroll
  for (int j = 0; j < 16; j++) { s += v[j]; ss += v[j] * v[j]; }
#pragma unroll
  for (int off = 32; off >= 1; off >>= 1) {
    s += __shfl_xor(s, off);
    ss += __shfl_xor(ss, off);
  }
  float mu = s * (1.f / 1024.f);
  float var = ss * (1.f / 1024.f) - mu * mu;
  float rs = rsqrtf(var + 1e-5f);
  u16x8 o0, o1;
#pragma unroll
  for (int c = 0; c < 4; c++) {
    float4 g = *(const float4*)(G + lane * 16 + c * 4);
    float4 bb = *(const float4*)(Bb + lane * 16 + c * 4);
    ushort_t* op = (c < 2) ? (ushort_t*)&o0 : (ushort_t*)&o1;
    int base = (c & 1) * 4;
    op[base + 0] = f2bf((v[c * 4 + 0] - mu) * rs * g.x + bb.x);
    op[base + 1] = f2bf((v[c * 4 + 1] - mu) * rs * g.y + bb.y);
    op[base + 2] = f2bf((v[c * 4 + 2] - mu) * rs * g.z + bb.z);
    op[base + 3] = f2bf((v[c * 4 + 3] - mu) * rs * g.w + bb.w);
  }
  ushort_t* yr = Y + (size_t)tok * 1024 + lane * 16;
  *(u16x8*)yr = o0;
  *(u16x8*)(yr + 8) = o1;
}

// ---------------- LayerNorm (bf16 in, bf16 out): 1 wave per token -----------
__global__ void __launch_bounds__(256) ln_bf16(const ushort_t* __restrict__ X,
                                               const float* __restrict__ G,
                                               const float* __restrict__ Bb,
                                               ushort_t* __restrict__ Y) {
  int tok = blockIdx.x * 4 + (threadIdx.x >> 6);
  int lane = threadIdx.x & 63;
  const ushort_t* xr = X + (size_t)tok * 1024 + lane * 16;
  u16x8 x0 = *(const u16x8*)xr;
  u16x8 x1 = *(const u16x8*)(xr + 8);
  float v[16];
  float s = 0.f, ss = 0.f;
#pragma unroll
  for (int j = 0; j < 8; j++) { v[j] = bf2f(x0[j]); v[8 + j] = bf2f(x1[j]); }
#pragma unroll
  for (int j = 0; j < 16; j++) { s += v[j]; ss += v[j] * v[j]; }
#pragma unroll
  for (int off = 32; off >= 1; off >>= 1) {
    s += __shfl_xor(s, off);
    ss += __shfl_xor(ss, off);
  }
  float mu = s * (1.f / 1024.f);
  float var = ss * (1.f / 1024.f) - mu * mu;
  float rs = rsqrtf(var + 1e-5f);
  u16x8 o0, o1;
#pragma unroll
  for (int c = 0; c < 4; c++) {
    float4 g = *(const float4*)(G + lane * 16 + c * 4);
    float4 bb = *(const float4*)(Bb + lane * 16 + c * 4);
    ushort_t* op = (c < 2) ? (ushort_t*)&o0 : (ushort_t*)&o1;
    int base = (c & 1) * 4;
    op[base + 0] = f2bf((v[c * 4 + 0] - mu) * rs * g.x + bb.x);
    op[base + 1] = f2bf((v[c * 4 + 1] - mu) * rs * g.y + bb.y);
    op[base + 2] = f2bf((v[c * 4 + 2] - mu) * rs * g.z + bb.z);
    op[base + 3] = f2bf((v[c * 4 + 3] - mu) * rs * g.w + bb.w);
  }
  ushort_t* yr = Y + (size_t)tok * 1024 + lane * 16;
  *(u16x8*)yr = o0;
  *(u16x8*)(yr + 8) = o1;
}

// ---------------- GEMM: C[M,N] = act(A[M,K] @ B[N,K]^T + bias) (+Res) -------
// 128x128 tile, template BK in {64,128}, 4 waves 2x2, 4x4 frags of 16x16x32
// bf16 MFMA, global_load_lds width=16 staging, K/BK K-iters.
// Tiles: row-major [128][BK], NG=BK/8 granules/row; granule g of row r at
//   slot g^(r&(NG-1)). Staging source col = ((t%NG)^((t/NG)&(NG-1)))*8;
//   frag read slot (c*4+quad)^(l16&(NG-1)). Per-16-lane group: 2-way bank
//   aliasing (free) for both BK variants.
// BK=64: __launch_bounds__(256,4), 32KB LDS, 4 blocks/CU (big-grid GEMMs).
// BK=128: __launch_bounds__(256,2), 64KB LDS, 2 blocks/CU — used where the
//   grid caps at 2 blocks/CU anyway (proj/ffn2, 512 blocks); halves the
//   number of per-K-step vmcnt(0)+barrier drains.
// Epilogue repack buffer aliases sA (safe after final K-loop barrier).
// swz=1: bijective XCD-blocked remap (requires gridDim.y % 8 == 0). XCD x
// (= lid%8, HW round-robin) owns m-tiles [x*ny/8,(x+1)*ny/8) x all n-tiles,
// so blocks sharing an A panel hit the same per-XCD L2.
template <int BK>
__global__ void __launch_bounds__(256, (BK == 64 ? 4 : 2))
gemm_bt(const ushort_t* __restrict__ A,
        const ushort_t* __restrict__ Bw,
        const float* __restrict__ bias,
        const float* __restrict__ ResF,
        const ushort_t* __restrict__ ResB,
        ushort_t* __restrict__ Cb,
        float* __restrict__ Cf,
        int M, int N, int K, int act, int swz) {
  constexpr int NG = BK / 8;        // granules per row (8 or 16)
  constexpr int GM = NG - 1;        // XOR mask
  constexpr int RPP = 2048 / BK;    // rows staged per pass (32 or 16)
  constexpr int NP = BK / 16;       // passes per tile (4 or 8)
  constexpr int NC = BK / 32;       // k-chunks per K-step (2 or 4)
  __shared__ __align__(16) ushort_t sAB[2 * 128 * BK];
  ushort_t* sA = sAB;
  ushort_t* sB = sAB + 128 * BK;
  int t = threadIdx.x;
  int wave = t >> 6, lane = t & 63;
  int quad = lane >> 4, l16 = lane & 15;
  int wm = (wave & 1) * 64, wn = (wave >> 1) * 64;

  int bx = blockIdx.x, by = blockIdx.y;
  if (swz) {
    int lid = by * gridDim.x + bx;
    int xcd = lid & 7, slot = lid >> 3;
    int mchunk = gridDim.y >> 3;           // m-tiles per XCD
    by = xcd * mchunk + slot / gridDim.x;
    bx = slot % gridDim.x;
  }
  int m0 = by * 128, n0 = bx * 128;

  f32x4 zero = {0.f, 0.f, 0.f, 0.f};
  f32x4 acc[4][4];
#pragma unroll
  for (int i = 0; i < 4; i++)
#pragma unroll
    for (int j = 0; j < 4; j++) acc[i][j] = zero;

  // staging: pass p, thread t covers LDS row p*RPP+(t/NG), slot t%NG;
  // source granule = slot ^ (row & GM) = (t%NG) ^ ((t/NG)&GM)  (p*RPP%NG==0)
  int srow = t / NG;
  int scol = ((t & GM) ^ (srow & GM)) * 8;
  const ushort_t* gA = A + (size_t)(m0 + srow) * K + scol;
  const ushort_t* gB = Bw + (size_t)(n0 + srow) * K + scol;

  for (int k0 = 0; k0 < K; k0 += BK) {
#pragma unroll
    for (int p = 0; p < NP; p++) {
      async_ld16(gA + (size_t)p * RPP * K + k0, sA + p * 2048 + wave * 512);
      async_ld16(gB + (size_t)p * RPP * K + k0, sB + p * 2048 + wave * 512);
    }
    __syncthreads();
#pragma unroll
    for (int c = 0; c < NC; c++) {
      int col = (((c * 4 + quad) ^ (l16 & GM)) * 8);
      bf16x8 af[4], bfr[4];
#pragma unroll
      for (int i = 0; i < 4; i++) {
        af[i]  = *(const bf16x8*)(sA + (wm + i * 16 + l16) * BK + col);
        bfr[i] = *(const bf16x8*)(sB + (wn + i * 16 + l16) * BK + col);
      }
#pragma unroll
      for (int mi = 0; mi < 4; mi++)
#pragma unroll
        for (int ni = 0; ni < 4; ni++)
          acc[mi][ni] = __builtin_amdgcn_mfma_f32_16x16x32_bf16(af[mi], bfr[ni], acc[mi][ni], 0, 0, 0);
    }
    __syncthreads();
  }

  // epilogue: C/D layout row = quad*4+r, col = l16 (m89/m91-verified)
  float bv[4];
#pragma unroll
  for (int ni = 0; ni < 4; ni++) bv[ni] = bias[n0 + wn + ni * 16 + l16];

  if (Cf) {
    // f32 output path (ffn2): scalar dword stores, 64B/quad coalesced
#pragma unroll
    for (int mi = 0; mi < 4; mi++) {
      int row = m0 + wm + mi * 16 + quad * 4;
#pragma unroll
      for (int ni = 0; ni < 4; ni++) {
        int col = n0 + wn + ni * 16 + l16;
#pragma unroll
        for (int r = 0; r < 4; r++) {
          size_t idx = (size_t)(row + r) * N + col;
          float vv = acc[mi][ni][r] + bv[ni];
          if (act) vv = gelu_f(vv);
          if (ResB) vv += bf2f(ResB[idx]);
          Cf[idx] = vv;
        }
      }
    }
  } else {
    // bf16 output path: per-wave LDS repack (aliases sA; all K-loop reads
    // completed at final barrier) -> 16B/lane stores
    ushort_t* eb = sAB + wave * (16 * 72);
    int lr = lane >> 2, lc = (lane & 3) * 8;
#pragma unroll
    for (int mi = 0; mi < 4; mi++) {
      int row = m0 + wm + mi * 16;
#pragma unroll
      for (int ni = 0; ni < 4; ni++)
#pragma unroll
        for (int r = 0; r < 4; r++) {
          float vv = acc[mi][ni][r] + bv[ni];
          if (act) vv = gelu_f(vv);
          eb[(quad * 4 + r) * 72 + ni * 16 + l16] = f2bf(vv);
        }
      // same-wave ds write->read (in-order); coalesced u16x8 global stores
#pragma unroll
      for (int hc = 0; hc < 64; hc += 32) {
        u16x8 o = *(const u16x8*)(eb + lr * 72 + hc + lc);
        size_t gidx = (size_t)(row + lr) * N + n0 + wn + hc + lc;
        if (ResF) {
          float4 ra = *(const float4*)(ResF + gidx);
          float4 rb = *(const float4*)(ResF + gidx + 4);
          u16x8 o2;
          o2[0] = f2bf(bf2f(o[0]) + ra.x); o2[1] = f2bf(bf2f(o[1]) + ra.y);
          o2[2] = f2bf(bf2f(o[2]) + ra.z); o2[3] = f2bf(bf2f(o[3]) + ra.w);
          o2[4] = f2bf(bf2f(o[4]) + rb.x); o2[5] = f2bf(bf2f(o[5]) + rb.y);
          o2[6] = f2bf(bf2f(o[6]) + rb.z); o2[7] = f2bf(bf2f(o[7]) + rb.w);
          *(u16x8*)(Cb + gidx) = o2;
        } else {
          *(u16x8*)(Cb + gidx) = o;
        }
      }
    }
  }
}

// ---------------- V transpose: qkv V-part [token, 64] -> Vt[b,h,64,1024] ----
__global__ void __launch_bounds__(256) vtrans(const ushort_t* __restrict__ qkv,
                                              ushort_t* __restrict__ Vt) {
  __shared__ ushort_t tile[64][72];
  int t = threadIdx.x;
  int bh = blockIdx.y;
  int b = bh >> 4, h = bh & 15;
  int n0 = blockIdx.x * 64;
  int r = t >> 3;
  int c8 = (t & 7) * 8;
  const ushort_t* src = qkv + ((size_t)(b * 1024 + n0)) * 3072 + 2048 + h * 64;
#pragma unroll
  for (int rr = r; rr < 64; rr += 32) {
    u16x8 d = *(const u16x8*)(src + (size_t)rr * 3072 + c8);
#pragma unroll
    for (int j = 0; j < 8; j++) tile[rr][c8 + j] = d[j];
  }
  __syncthreads();
#pragma unroll
  for (int hh = r; hh < 64; hh += 32) {
    u16x8 o;
#pragma unroll
    for (int j = 0; j < 8; j++) o[j] = tile[c8 + j][hh];
    *(u16x8*)(Vt + ((size_t)bh * 64 + hh) * 1024 + n0 + c8) = o;
  }
}

// ---------------- Flash attention, S^T formulation (unchanged from R5) ------
__global__ void __launch_bounds__(256) attn_kernel(const ushort_t* __restrict__ qkv,
                                                   const ushort_t* __restrict__ Vt,
                                                   ushort_t* __restrict__ ctx) {
  __shared__ __align__(16) ushort_t sK[128 * 64];
  __shared__ __align__(16) ushort_t sV[64 * 128];
  __shared__ __align__(16) ushort_t sP[4 * 16 * 144];
  int t = threadIdx.x, wave = t >> 6, lane = t & 63;
  int quad = lane >> 4, l16 = lane & 15;
  int bh = blockIdx.y, b = bh >> 4, h = bh & 15;
  int q0 = blockIdx.x * 64 + wave * 16;
  size_t tokbase = (size_t)b * 1024;

  const ushort_t* qrow = qkv + (tokbase + q0 + l16) * 3072 + h * 64;
  bf16x8 qf0 = *(const bf16x8*)(qrow + quad * 8);
  bf16x8 qf1 = *(const bf16x8*)(qrow + 32 + quad * 8);

  f32x4 zero = {0.f, 0.f, 0.f, 0.f};
  f32x4 O[4];
#pragma unroll
  for (int i = 0; i < 4; i++) O[i] = zero;
  float m = -3.0e38f, l = 0.f;

  int kvlK = wave * 32 + (lane >> 3);
  int hdKx = lane & 7;
  ushort_t* pw = sP + wave * (16 * 144);

  for (int kv0 = 0; kv0 < 1024; kv0 += 128) {
#pragma unroll
    for (int j = 0; j < 4; j++) {
      int kvl = kvlK + j * 8;
      int hd = (hdKx ^ (kvl & 7)) * 8;
      async_ld16(qkv + (tokbase + kv0 + kvl) * 3072 + 1024 + h * 64 + hd,
                 sK + wave * 2048 + j * 512);
      int hdv = wave * 16 + j * 4 + (lane >> 4);
      int kvloc = ((lane & 15) ^ (hdv & 15)) * 8;
      async_ld16(Vt + ((size_t)bh * 64 + hdv) * 1024 + kv0 + kvloc,
                 sV + wave * 2048 + j * 512);
    }
    __syncthreads();

    f32x4 st[8];
#pragma unroll
    for (int s = 0; s < 8; s++) {
      bf16x8 kf0 = *(const bf16x8*)(sK + (s * 16 + l16) * 64 + ((quad ^ (l16 & 7)) * 8));
      bf16x8 kf1 = *(const bf16x8*)(sK + (s * 16 + l16) * 64 + (((4 + quad) ^ (l16 & 7)) * 8));
      st[s] = __builtin_amdgcn_mfma_f32_16x16x32_bf16(kf0, qf0, zero, 0, 0, 0);
      st[s] = __builtin_amdgcn_mfma_f32_16x16x32_bf16(kf1, qf1, st[s], 0, 0, 0);
    }
    f32x4 mx4 = st[0];
#pragma unroll
    for (int s = 1; s < 8; s++)
#pragma unroll
      for (int r = 0; r < 4; r++) mx4[r] = fmaxf(mx4[r], st[s][r]);
    float mx = fmaxf(fmaxf(mx4[0], mx4[1]), fmaxf(mx4[2], mx4[3]));
    mx = fmaxf(mx, __shfl_xor(mx, 16));
    mx = fmaxf(mx, __shfl_xor(mx, 32));
    float mnew = fmaxf(m, mx * 0.125f);
    float alpha = __expf(m - mnew);
    m = mnew;
    float rs = 0.f;
#pragma unroll
    for (int s = 0; s < 8; s++)
#pragma unroll
      for (int r = 0; r < 4; r++) {
        st[s][r] = __expf(fmaf(st[s][r], 0.125f, -m));
        rs += st[s][r];
      }
    rs += __shfl_xor(rs, 16);
    rs += __shfl_xor(rs, 32);
    l = l * alpha + rs;
#pragma unroll
    for (int s = 0; s < 8; s++) {
      uint2 pk;
      pk.x = __builtin_amdgcn_perm(__float_as_uint(st[s][1]), __float_as_uint(st[s][0]), 0x07060302u);
      pk.y = __builtin_amdgcn_perm(__float_as_uint(st[s][3]), __float_as_uint(st[s][2]), 0x07060302u);
      *(uint2*)(pw + l16 * 144 + s * 16 + quad * 4) = pk;
    }
#pragma unroll
    for (int ti = 0; ti < 4; ti++)
#pragma unroll
      for (int r = 0; r < 4; r++) O[ti][r] *= alpha;
#pragma unroll
    for (int c = 0; c < 4; c++) {
      bf16x8 pf = *(const bf16x8*)(pw + l16 * 144 + c * 32 + quad * 8);
#pragma unroll
      for (int ti = 0; ti < 4; ti++) {
        bf16x8 vf = *(const bf16x8*)(sV + (ti * 16 + l16) * 128 + (((c * 4 + quad) ^ l16) * 8));
        O[ti] = __builtin_amdgcn_mfma_f32_16x16x32_bf16(vf, pf, O[ti], 0, 0, 0);
      }
    }
    __syncthreads();
  }
  float inv = 1.0f / l;
  ushort_t* cb = ctx + (tokbase + q0 + l16) * 1024 + h * 64;
#pragma unroll
  for (int ti = 0; ti < 4; ti++) {
    uint2 pk;
    pk.x = (unsigned int)f2bf(O[ti][0] * inv) | ((unsigned int)f2bf(O[ti][1] * inv) << 16);
    pk.y = (unsigned int)f2bf(O[ti][2] * inv) | ((unsigned int)f2bf(O[ti][3] * inv) << 16);
    *(uint2*)(cb + ti * 16 + quad * 4) = pk;
  }
}

extern "C" void kernel_launch(void* const* d_in, const int* in_sizes, int n_in,
                              void* d_out, int out_size, void* d_ws, size_t ws_size,
                              hipStream_t stream) {
  (void)in_sizes; (void)n_in; (void)out_size; (void)ws_size;
  const float* x     = (const float*)d_in[0];
  const float* ln1g  = (const float*)d_in[1];
  const float* ln1b  = (const float*)d_in[2];
  const float* ln2g  = (const float*)d_in[3];
  const float* ln2b  = (const float*)d_in[4];
  const float* Wqkv  = (const float*)d_in[5];
  const float* bqkv  = (const float*)d_in[6];
  const float* Wproj = (const float*)d_in[7];
  const float* bproj = (const float*)d_in[8];
  const float* W1    = (const float*)d_in[9];
  const float* b1    = (const float*)d_in[10];
  const float* W2    = (const float*)d_in[11];
  const float* b2    = (const float*)d_in[12];
  float* out = (float*)d_out;
  char* ws = (char*)d_ws;
  const size_t MB = 1u << 20;
  ushort_t* Wqkv_b  = (ushort_t*)(ws + 0);
  ushort_t* Wproj_b = (ushort_t*)(ws + 6 * MB);
  ushort_t* h1      = (ushort_t*)(ws + 8 * MB);
  ushort_t* qkv     = (ushort_t*)(ws + 24 * MB);
  ushort_t* Vt      = (ushort_t*)(ws + 72 * MB);
  ushort_t* ctx     = (ushort_t*)(ws + 8 * MB);
  ushort_t* out1    = (ushort_t*)(ws + 24 * MB);
  ushort_t* W1_b    = (ushort_t*)(ws + 0);
  ushort_t* h2      = (ushort_t*)(ws + 8 * MB);
  ushort_t* ff1     = (ushort_t*)(ws + 40 * MB);
  ushort_t* W2_b    = (ushort_t*)(ws + 0);

  cvt_f32_bf16<<<1536, 256, 0, stream>>>(Wqkv, Wqkv_b, 3 * 1024 * 1024);
  cvt_f32_bf16<<<512, 256, 0, stream>>>(Wproj, Wproj_b, 1024 * 1024);
  ln_f32<<<2048, 256, 0, stream>>>(x, ln1g, ln1b, h1);
  gemm_bt<64><<<dim3(24, 64), 256, 0, stream>>>(h1, Wqkv_b, bqkv, nullptr, nullptr, qkv, nullptr, 8192, 3072, 1024, 0, 0);
  vtrans<<<dim3(16, 128), 256, 0, stream>>>(qkv, Vt);
  attn_kernel<<<dim3(16, 128), 256, 0, stream>>>(qkv, Vt, ctx);
  gemm_bt<128><<<dim3(8, 64), 256, 0, stream>>>(ctx, Wproj_b, bproj, x, nullptr, out1, nullptr, 8192, 1024, 1024, 0, 0);
  cvt_f32_bf16<<<2048, 256, 0, stream>>>(W1, W1_b, 4 * 1024 * 1024);
  ln_bf16<<<2048, 256, 0, stream>>>(out1, ln2g, ln2b, h2);
  gemm_bt<64><<<dim3(32, 64), 256, 0, stream>>>(h2, W1_b, b1, nullptr, nullptr, ff1, nullptr, 8192, 4096, 1024, 1, 0);
  cvt_f32_bf16<<<2048, 256, 0, stream>>>(W2, W2_b, 4 * 1024 * 1024);
  gemm_bt<128><<<dim3(8, 64), 256, 0, stream>>>(ff1, W2_b, b2, nullptr, out1, nullptr, out, 8192, 1024, 4096, 1, 1);
}

// Round 3
// 476.890 us; speedup vs baseline: 1.0947x; 1.0626x over previous
//
#include <hip/hip_runtime.h>

// Problem: B=8, N=1024, D=1024, H=16, HD=64, FF=4096. Tokens M = 8192.
// Inputs f32, OUTPUT f32. Internals bf16, f32 accumulation.
// Round 10: attention VALU/LDS push. R9 counters: attn is now the biggest
// dispatch (86.4us, VALUBusy 46% vs MfmaUtil 16%, 6.29M bank-conflict cy).
// (1) exp2-domain softmax (fold 0.125*log2e into the fma; saves a v_mul per
//     score elem), (2) defer-max THR=8 (skip O-rescale when max growth <=8,
//     T13), (3) sP stride 144->152 (4-way -> free 2-way bank conflicts on
//     P write+read), (4) s_setprio(1) around MFMA clusters (T5, +4-7% attn).
// Also merged Wqkv+Wproj cvt into one launch. GEMMs unchanged from R9.

typedef unsigned short ushort_t;
typedef __bf16 bf16x8 __attribute__((ext_vector_type(8)));
typedef float f32x4 __attribute__((ext_vector_type(4)));
typedef unsigned short u16x8 __attribute__((ext_vector_type(8)));

__device__ __forceinline__ void async_ld16(const void* g, void* l) {
  // global -> LDS direct, 16B per lane. LDS dst is wave-uniform base; HW
  // writes base + lane*16.
  __builtin_amdgcn_global_load_lds(
      (void __attribute__((address_space(1)))*)const_cast<void*>(g),
      (void __attribute__((address_space(3)))*)l, 16, 0, 0);
}

__device__ __forceinline__ float bf2f(ushort_t h) {
  union { unsigned int u; float f; } v;
  v.u = ((unsigned int)h) << 16;
  return v.f;
}
__device__ __forceinline__ ushort_t f2bf(float f) {
  union { float f; unsigned int u; } v;
  v.f = f;
  unsigned int r = v.u + 0x7FFFu + ((v.u >> 16) & 1u);  // RNE
  return (ushort_t)(r >> 16);
}
// 2^x via HW v_exp_f32 (D = 2^S0 per ISA); guarded fallback keeps semantics.
__device__ __forceinline__ float fast_exp2(float x) {
#if __has_builtin(__builtin_amdgcn_exp2f)
  return __builtin_amdgcn_exp2f(x);
#else
  return __expf(x * 0.6931471805599453f);
#endif
}
// tanh-form GELU (~3e-4 dev from exact erf; 0.078 threshold headroom)
__device__ __forceinline__ float gelu_f(float x) {
  float y = 0.7978845608028654f * (x + 0.044715f * x * x * x);
  float e = __expf(2.0f * y);
  float t = 1.0f - 2.0f / (e + 1.0f);
  return 0.5f * x * (1.0f + t);
}

// ---------------- f32 -> bf16 weight conversion (8 elems/thread) ------------
__global__ void __launch_bounds__(256) cvt_f32_bf16(const float* __restrict__ src,
                                                    ushort_t* __restrict__ dst, int n) {
  int i = (blockIdx.x * 256 + threadIdx.x) * 8;
  if (i >= n) return;
  float4 a = *(const float4*)(src + i);
  float4 b = *(const float4*)(src + i + 4);
  u16x8 o;
  o[0] = f2bf(a.x); o[1] = f2bf(a.y); o[2] = f2bf(a.z); o[3] = f2bf(a.w);
  o[4] = f2bf(b.x); o[5] = f2bf(b.y); o[6] = f2bf(b.z); o[7] = f2bf(b.w);
  *(u16x8*)(dst + i) = o;
}

// two-buffer variant: one launch for Wqkv (n0) + Wproj (n1), non-aliasing dsts
__global__ void __launch_bounds__(256) cvt_f32_bf16_2(const float* __restrict__ s0,
                                                      ushort_t* __restrict__ d0, int n0,
                                                      const float* __restrict__ s1,
                                                      ushort_t* __restrict__ d1, int n1) {
  int i = (blockIdx.x * 256 + threadIdx.x) * 8;
  const float* src;
  ushort_t* dst;
  if (i < n0) {
    src = s0 + i; dst = d0 + i;
  } else {
    int j = i - n0;
    if (j >= n1) return;
    src = s1 + j; dst = d1 + j;
  }
  float4 a = *(const float4*)(src);
  float4 b = *(const float4*)(src + 4);
  u16x8 o;
  o[0] = f2bf(a.x); o[1] = f2bf(a.y); o[2] = f2bf(a.z); o[3] = f2bf(a.w);
  o[4] = f2bf(b.x); o[5] = f2bf(b.y); o[6] = f2bf(b.z); o[7] = f2bf(b.w);
  *(u16x8*)dst = o;
}

// ---------------- LayerNorm (f32 in, bf16 out): 1 wave per token ------------
__global__ void __launch_bounds__(256) ln_f32(const float* __restrict__ X,
                                              const float* __restrict__ G,
                                              const float* __restrict__ Bb,
                                              ushort_t* __restrict__ Y) {
  int tok = blockIdx.x * 4 + (threadIdx.x >> 6);
  int lane = threadIdx.x & 63;
  const float* xr = X + (size_t)tok * 1024 + lane * 16;
  float v[16];
#pragma unroll
  for (int c = 0; c < 4; c++) {
    float4 a = *(const float4*)(xr + c * 4);
    v[c * 4 + 0] = a.x; v[c * 4 + 1] = a.y; v[c * 4 + 2] = a.z; v[c * 4 + 3] = a.w;
  }
  float s = 0.f, ss = 0.f;
#pragma unroll
  for (int j = 0; j < 16; j++) { s += v[j]; ss += v[j] * v[j]; }
#pragma unroll
  for (int off = 32; off >= 1; off >>= 1) {
    s += __shfl_xor(s, off);
    ss += __shfl_xor(ss, off);
  }
  float mu = s * (1.f / 1024.f);
  float var = ss * (1.f / 1024.f) - mu * mu;
  float rs = rsqrtf(var + 1e-5f);
  u16x8 o0, o1;
#pragma unroll
  for (int c = 0; c < 4; c++) {
    float4 g = *(const float4*)(G + lane * 16 + c * 4);
    float4 bb = *(const float4*)(Bb + lane * 16 + c * 4);
    ushort_t* op = (c < 2) ? (ushort_t*)&o0 : (ushort_t*)&o1;
    int base = (c & 1) * 4;
    op[base + 0] = f2bf((v[c * 4 + 0] - mu) * rs * g.x + bb.x);
    op[base + 1] = f2bf((v[c * 4 + 1] - mu) * rs * g.y + bb.y);
    op[base + 2] = f2bf((v[c * 4 + 2] - mu) * rs * g.z + bb.z);
    op[base + 3] = f2bf((v[c * 4 + 3] - mu) * rs * g.w + bb.w);
  }
  ushort_t* yr = Y + (size_t)tok * 1024 + lane * 16;
  *(u16x8*)yr = o0;
  *(u16x8*)(yr + 8) = o1;
}

// ---------------- LayerNorm (bf16 in, bf16 out): 1 wave per token -----------
__global__ void __launch_bounds__(256) ln_bf16(const ushort_t* __restrict__ X,
                                               const float* __restrict__ G,
                                               const float* __restrict__ Bb,
                                               ushort_t* __restrict__ Y) {
  int tok = blockIdx.x * 4 + (threadIdx.x >> 6);
  int lane = threadIdx.x & 63;
  const ushort_t* xr = X + (size_t)tok * 1024 + lane * 16;
  u16x8 x0 = *(const u16x8*)xr;
  u16x8 x1 = *(const u16x8*)(xr + 8);
  float v[16];
  float s = 0.f, ss = 0.f;
#pragma unroll
  for (int j = 0; j < 8; j++) { v[j] = bf2f(x0[j]); v[8 + j] = bf2f(x1[j]); }
#pragma unroll
  for (int j = 0; j < 16; j++) { s += v[j]; ss += v[j] * v[j]; }
#pragma unroll
  for (int off = 32; off >= 1; off >>= 1) {
    s += __shfl_xor(s, off);
    ss += __shfl_xor(ss, off);
  }
  float mu = s * (1.f / 1024.f);
  float var = ss * (1.f / 1024.f) - mu * mu;
  float rs = rsqrtf(var + 1e-5f);
  u16x8 o0, o1;
#pragma unroll
  for (int c = 0; c < 4; c++) {
    float4 g = *(const float4*)(G + lane * 16 + c * 4);
    float4 bb = *(const float4*)(Bb + lane * 16 + c * 4);
    ushort_t* op = (c < 2) ? (ushort_t*)&o0 : (ushort_t*)&o1;
    int base = (c & 1) * 4;
    op[base + 0] = f2bf((v[c * 4 + 0] - mu) * rs * g.x + bb.x);
    op[base + 1] = f2bf((v[c * 4 + 1] - mu) * rs * g.y + bb.y);
    op[base + 2] = f2bf((v[c * 4 + 2] - mu) * rs * g.z + bb.z);
    op[base + 3] = f2bf((v[c * 4 + 3] - mu) * rs * g.w + bb.w);
  }
  ushort_t* yr = Y + (size_t)tok * 1024 + lane * 16;
  *(u16x8*)yr = o0;
  *(u16x8*)(yr + 8) = o1;
}

// ---------------- GEMM: C[M,N] = act(A[M,K] @ B[N,K]^T + bias) (+Res) -------
// 128x128 tile, template BK in {64,128}, 4 waves 2x2, 4x4 frags of 16x16x32
// bf16 MFMA, global_load_lds width=16 staging, K/BK K-iters.
// Tiles: row-major [128][BK], NG=BK/8 granules/row; granule g of row r at
//   slot g^(r&(NG-1)). Staging source col = ((t%NG)^((t/NG)&(NG-1)))*8;
//   frag read slot (c*4+quad)^(l16&(NG-1)). Per-16-lane group: 2-way bank
//   aliasing (free) for both BK variants.
// BK=64: __launch_bounds__(256,4), 32KB LDS, 4 blocks/CU (big-grid GEMMs).
// BK=128: __launch_bounds__(256,2), 64KB LDS, 2 blocks/CU — used where the
//   grid caps at 2 blocks/CU anyway (proj/ffn2, 512 blocks); halves the
//   number of per-K-step vmcnt(0)+barrier drains.
// Epilogue repack buffer aliases sA (safe after final K-loop barrier).
// swz=1: bijective XCD-blocked remap (requires gridDim.y % 8 == 0). XCD x
// (= lid%8, HW round-robin) owns m-tiles [x*ny/8,(x+1)*ny/8) x all n-tiles,
// so blocks sharing an A panel hit the same per-XCD L2.
template <int BK>
__global__ void __launch_bounds__(256, (BK == 64 ? 4 : 2))
gemm_bt(const ushort_t* __restrict__ A,
        const ushort_t* __restrict__ Bw,
        const float* __restrict__ bias,
        const float* __restrict__ ResF,
        const ushort_t* __restrict__ ResB,
        ushort_t* __restrict__ Cb,
        float* __restrict__ Cf,
        int M, int N, int K, int act, int swz) {
  constexpr int NG = BK / 8;        // granules per row (8 or 16)
  constexpr int GM = NG - 1;        // XOR mask
  constexpr int RPP = 2048 / BK;    // rows staged per pass (32 or 16)
  constexpr int NP = BK / 16;       // passes per tile (4 or 8)
  constexpr int NC = BK / 32;       // k-chunks per K-step (2 or 4)
  __shared__ __align__(16) ushort_t sAB[2 * 128 * BK];
  ushort_t* sA = sAB;
  ushort_t* sB = sAB + 128 * BK;
  int t = threadIdx.x;
  int wave = t >> 6, lane = t & 63;
  int quad = lane >> 4, l16 = lane & 15;
  int wm = (wave & 1) * 64, wn = (wave >> 1) * 64;

  int bx = blockIdx.x, by = blockIdx.y;
  if (swz) {
    int lid = by * gridDim.x + bx;
    int xcd = lid & 7, slot = lid >> 3;
    int mchunk = gridDim.y >> 3;           // m-tiles per XCD
    by = xcd * mchunk + slot / gridDim.x;
    bx = slot % gridDim.x;
  }
  int m0 = by * 128, n0 = bx * 128;

  f32x4 zero = {0.f, 0.f, 0.f, 0.f};
  f32x4 acc[4][4];
#pragma unroll
  for (int i = 0; i < 4; i++)
#pragma unroll
    for (int j = 0; j < 4; j++) acc[i][j] = zero;

  // staging: pass p, thread t covers LDS row p*RPP+(t/NG), slot t%NG;
  // source granule = slot ^ (row & GM) = (t%NG) ^ ((t/NG)&GM)  (p*RPP%NG==0)
  int srow = t / NG;
  int scol = ((t & GM) ^ (srow & GM)) * 8;
  const ushort_t* gA = A + (size_t)(m0 + srow) * K + scol;
  const ushort_t* gB = Bw + (size_t)(n0 + srow) * K + scol;

  for (int k0 = 0; k0 < K; k0 += BK) {
#pragma unroll
    for (int p = 0; p < NP; p++) {
      async_ld16(gA + (size_t)p * RPP * K + k0, sA + p * 2048 + wave * 512);
      async_ld16(gB + (size_t)p * RPP * K + k0, sB + p * 2048 + wave * 512);
    }
    __syncthreads();
#pragma unroll
    for (int c = 0; c < NC; c++) {
      int col = (((c * 4 + quad) ^ (l16 & GM)) * 8);
      bf16x8 af[4], bfr[4];
#pragma unroll
      for (int i = 0; i < 4; i++) {
        af[i]  = *(const bf16x8*)(sA + (wm + i * 16 + l16) * BK + col);
        bfr[i] = *(const bf16x8*)(sB + (wn + i * 16 + l16) * BK + col);
      }
#pragma unroll
      for (int mi = 0; mi < 4; mi++)
#pragma unroll
        for (int ni = 0; ni < 4; ni++)
          acc[mi][ni] = __builtin_amdgcn_mfma_f32_16x16x32_bf16(af[mi], bfr[ni], acc[mi][ni], 0, 0, 0);
    }
    __syncthreads();
  }

  // epilogue: C/D layout row = quad*4+r, col = l16 (m89/m91-verified)
  float bv[4];
#pragma unroll
  for (int ni = 0; ni < 4; ni++) bv[ni] = bias[n0 + wn + ni * 16 + l16];

  if (Cf) {
    // f32 output path (ffn2): scalar dword stores, 64B/quad coalesced
#pragma unroll
    for (int mi = 0; mi < 4; mi++) {
      int row = m0 + wm + mi * 16 + quad * 4;
#pragma unroll
      for (int ni = 0; ni < 4; ni++) {
        int col = n0 + wn + ni * 16 + l16;
#pragma unroll
        for (int r = 0; r < 4; r++) {
          size_t idx = (size_t)(row + r) * N + col;
          float vv = acc[mi][ni][r] + bv[ni];
          if (act) vv = gelu_f(vv);
          if (ResB) vv += bf2f(ResB[idx]);
          Cf[idx] = vv;
        }
      }
    }
  } else {
    // bf16 output path: per-wave LDS repack (aliases sA; all K-loop reads
    // completed at final barrier) -> 16B/lane stores
    ushort_t* eb = sAB + wave * (16 * 72);
    int lr = lane >> 2, lc = (lane & 3) * 8;
#pragma unroll
    for (int mi = 0; mi < 4; mi++) {
      int row = m0 + wm + mi * 16;
#pragma unroll
      for (int ni = 0; ni < 4; ni++)
#pragma unroll
        for (int r = 0; r < 4; r++) {
          float vv = acc[mi][ni][r] + bv[ni];
          if (act) vv = gelu_f(vv);
          eb[(quad * 4 + r) * 72 + ni * 16 + l16] = f2bf(vv);
        }
      // same-wave ds write->read (in-order); coalesced u16x8 global stores
#pragma unroll
      for (int hc = 0; hc < 64; hc += 32) {
        u16x8 o = *(const u16x8*)(eb + lr * 72 + hc + lc);
        size_t gidx = (size_t)(row + lr) * N + n0 + wn + hc + lc;
        if (ResF) {
          float4 ra = *(const float4*)(ResF + gidx);
          float4 rb = *(const float4*)(ResF + gidx + 4);
          u16x8 o2;
          o2[0] = f2bf(bf2f(o[0]) + ra.x); o2[1] = f2bf(bf2f(o[1]) + ra.y);
          o2[2] = f2bf(bf2f(o[2]) + ra.z); o2[3] = f2bf(bf2f(o[3]) + ra.w);
          o2[4] = f2bf(bf2f(o[4]) + rb.x); o2[5] = f2bf(bf2f(o[5]) + rb.y);
          o2[6] = f2bf(bf2f(o[6]) + rb.z); o2[7] = f2bf(bf2f(o[7]) + rb.w);
          *(u16x8*)(Cb + gidx) = o2;
        } else {
          *(u16x8*)(Cb + gidx) = o;
        }
      }
    }
  }
}

// ---------------- V transpose: qkv V-part [token, 64] -> Vt[b,h,64,1024] ----
__global__ void __launch_bounds__(256) vtrans(const ushort_t* __restrict__ qkv,
                                              ushort_t* __restrict__ Vt) {
  __shared__ ushort_t tile[64][72];
  int t = threadIdx.x;
  int bh = blockIdx.y;
  int b = bh >> 4, h = bh & 15;
  int n0 = blockIdx.x * 64;
  int r = t >> 3;
  int c8 = (t & 7) * 8;
  const ushort_t* src = qkv + ((size_t)(b * 1024 + n0)) * 3072 + 2048 + h * 64;
#pragma unroll
  for (int rr = r; rr < 64; rr += 32) {
    u16x8 d = *(const u16x8*)(src + (size_t)rr * 3072 + c8);
#pragma unroll
    for (int j = 0; j < 8; j++) tile[rr][c8 + j] = d[j];
  }
  __syncthreads();
#pragma unroll
  for (int hh = r; hh < 64; hh += 32) {
    u16x8 o;
#pragma unroll
    for (int j = 0; j < 8; j++) o[j] = tile[c8 + j][hh];
    *(u16x8*)(Vt + ((size_t)bh * 64 + hh) * 1024 + n0 + c8) = o;
  }
}

// ---------------- Flash attention, S^T formulation --------------------------
// R10: exp2-domain softmax, defer-max (THR=8 in log2 domain), sP stride 152
// (2-way bank aliasing on P write/read, was 4-way at 144), setprio around
// MFMA clusters. SC2 = 0.125 * log2(e); p = 2^(s*SC2 - m2) == e^(0.125 s - m).
__global__ void __launch_bounds__(256) attn_kernel(const ushort_t* __restrict__ qkv,
                                                   const ushort_t* __restrict__ Vt,
                                                   ushort_t* __restrict__ ctx) {
  __shared__ __align__(16) ushort_t sK[128 * 64];
  __shared__ __align__(16) ushort_t sV[64 * 128];
  __shared__ __align__(16) ushort_t sP[4 * 16 * 152];
  int t = threadIdx.x, wave = t >> 6, lane = t & 63;
  int quad = lane >> 4, l16 = lane & 15;
  int bh = blockIdx.y, b = bh >> 4, h = bh & 15;
  int q0 = blockIdx.x * 64 + wave * 16;
  size_t tokbase = (size_t)b * 1024;
  const float SC2 = 0.18033688011112042f;  // 0.125 * log2(e)

  const ushort_t* qrow = qkv + (tokbase + q0 + l16) * 3072 + h * 64;
  bf16x8 qf0 = *(const bf16x8*)(qrow + quad * 8);
  bf16x8 qf1 = *(const bf16x8*)(qrow + 32 + quad * 8);

  f32x4 zero = {0.f, 0.f, 0.f, 0.f};
  f32x4 O[4];
#pragma unroll
  for (int i = 0; i < 4; i++) O[i] = zero;
  float m2 = -3.0e38f, l = 0.f;

  int kvlK = wave * 32 + (lane >> 3);
  int hdKx = lane & 7;
  ushort_t* pw = sP + wave * (16 * 152);

  for (int kv0 = 0; kv0 < 1024; kv0 += 128) {
#pragma unroll
    for (int j = 0; j < 4; j++) {
      int kvl = kvlK + j * 8;
      int hd = (hdKx ^ (kvl & 7)) * 8;
      async_ld16(qkv + (tokbase + kv0 + kvl) * 3072 + 1024 + h * 64 + hd,
                 sK + wave * 2048 + j * 512);
      int hdv = wave * 16 + j * 4 + (lane >> 4);
      int kvloc = ((lane & 15) ^ (hdv & 15)) * 8;
      async_ld16(Vt + ((size_t)bh * 64 + hdv) * 1024 + kv0 + kvloc,
                 sV + wave * 2048 + j * 512);
    }
    __syncthreads();

    f32x4 st[8];
    __builtin_amdgcn_s_setprio(1);
#pragma unroll
    for (int s = 0; s < 8; s++) {
      bf16x8 kf0 = *(const bf16x8*)(sK + (s * 16 + l16) * 64 + ((quad ^ (l16 & 7)) * 8));
      bf16x8 kf1 = *(const bf16x8*)(sK + (s * 16 + l16) * 64 + (((4 + quad) ^ (l16 & 7)) * 8));
      st[s] = __builtin_amdgcn_mfma_f32_16x16x32_bf16(kf0, qf0, zero, 0, 0, 0);
      st[s] = __builtin_amdgcn_mfma_f32_16x16x32_bf16(kf1, qf1, st[s], 0, 0, 0);
    }
    __builtin_amdgcn_s_setprio(0);
    f32x4 mx4 = st[0];
#pragma unroll
    for (int s = 1; s < 8; s++)
#pragma unroll
      for (int r = 0; r < 4; r++) mx4[r] = fmaxf(mx4[r], st[s][r]);
    float mx = fmaxf(fmaxf(mx4[0], mx4[1]), fmaxf(mx4[2], mx4[3]));
    mx = fmaxf(mx, __shfl_xor(mx, 16));
    mx = fmaxf(mx, __shfl_xor(mx, 32));
    float mx2 = mx * SC2;
    // defer-max: only rescale when some q-row's max grew by >8 (log2 domain).
    // Skipped => p bounded by 2^8 = 256; f32 l and bf16 P tolerate it.
    if (!__all(mx2 - m2 <= 8.0f)) {
      float mnew2 = fmaxf(m2, mx2);
      float alpha = fast_exp2(m2 - mnew2);
      m2 = mnew2;
      l *= alpha;
#pragma unroll
      for (int ti = 0; ti < 4; ti++)
#pragma unroll
        for (int r = 0; r < 4; r++) O[ti][r] *= alpha;
    }
    float rs = 0.f;
#pragma unroll
    for (int s = 0; s < 8; s++)
#pragma unroll
      for (int r = 0; r < 4; r++) {
        st[s][r] = fast_exp2(fmaf(st[s][r], SC2, -m2));
        rs += st[s][r];
      }
    rs += __shfl_xor(rs, 16);
    rs += __shfl_xor(rs, 32);
    l += rs;
#pragma unroll
    for (int s = 0; s < 8; s++) {
      uint2 pk;
      pk.x = __builtin_amdgcn_perm(__float_as_uint(st[s][1]), __float_as_uint(st[s][0]), 0x07060302u);
      pk.y = __builtin_amdgcn_perm(__float_as_uint(st[s][3]), __float_as_uint(st[s][2]), 0x07060302u);
      *(uint2*)(pw + l16 * 152 + s * 16 + quad * 4) = pk;
    }
    __builtin_amdgcn_s_setprio(1);
#pragma unroll
    for (int c = 0; c < 4; c++) {
      bf16x8 pf = *(const bf16x8*)(pw + l16 * 152 + c * 32 + quad * 8);
#pragma unroll
      for (int ti = 0; ti < 4; ti++) {
        bf16x8 vf = *(const bf16x8*)(sV + (ti * 16 + l16) * 128 + (((c * 4 + quad) ^ l16) * 8));
        O[ti] = __builtin_amdgcn_mfma_f32_16x16x32_bf16(vf, pf, O[ti], 0, 0, 0);
      }
    }
    __builtin_amdgcn_s_setprio(0);
    __syncthreads();
  }
  float inv = 1.0f / l;
  ushort_t* cb = ctx + (tokbase + q0 + l16) * 1024 + h * 64;
#pragma unroll
  for (int ti = 0; ti < 4; ti++) {
    uint2 pk;
    pk.x = (unsigned int)f2bf(O[ti][0] * inv) | ((unsigned int)f2bf(O[ti][1] * inv) << 16);
    pk.y = (unsigned int)f2bf(O[ti][2] * inv) | ((unsigned int)f2bf(O[ti][3] * inv) << 16);
    *(uint2*)(cb + ti * 16 + quad * 4) = pk;
  }
}

extern "C" void kernel_launch(void* const* d_in, const int* in_sizes, int n_in,
                              void* d_out, int out_size, void* d_ws, size_t ws_size,
                              hipStream_t stream) {
  (void)in_sizes; (void)n_in; (void)out_size; (void)ws_size;
  const float* x     = (const float*)d_in[0];
  const float* ln1g  = (const float*)d_in[1];
  const float* ln1b  = (const float*)d_in[2];
  const float* ln2g  = (const float*)d_in[3];
  const float* ln2b  = (const float*)d_in[4];
  const float* Wqkv  = (const float*)d_in[5];
  const float* bqkv  = (const float*)d_in[6];
  const float* Wproj = (const float*)d_in[7];
  const float* bproj = (const float*)d_in[8];
  const float* W1    = (const float*)d_in[9];
  const float* b1    = (const float*)d_in[10];
  const float* W2    = (const float*)d_in[11];
  const float* b2    = (const float*)d_in[12];
  float* out = (float*)d_out;
  char* ws = (char*)d_ws;
  const size_t MB = 1u << 20;
  ushort_t* Wqkv_b  = (ushort_t*)(ws + 0);
  ushort_t* Wproj_b = (ushort_t*)(ws + 6 * MB);
  ushort_t* h1      = (ushort_t*)(ws + 8 * MB);
  ushort_t* qkv     = (ushort_t*)(ws + 24 * MB);
  ushort_t* Vt      = (ushort_t*)(ws + 72 * MB);
  ushort_t* ctx     = (ushort_t*)(ws + 8 * MB);
  ushort_t* out1    = (ushort_t*)(ws + 24 * MB);
  ushort_t* W1_b    = (ushort_t*)(ws + 0);
  ushort_t* h2      = (ushort_t*)(ws + 8 * MB);
  ushort_t* ff1     = (ushort_t*)(ws + 40 * MB);
  ushort_t* W2_b    = (ushort_t*)(ws + 0);

  cvt_f32_bf16_2<<<2048, 256, 0, stream>>>(Wqkv, Wqkv_b, 3 * 1024 * 1024,
                                           Wproj, Wproj_b, 1024 * 1024);
  ln_f32<<<2048, 256, 0, stream>>>(x, ln1g, ln1b, h1);
  gemm_bt<64><<<dim3(24, 64), 256, 0, stream>>>(h1, Wqkv_b, bqkv, nullptr, nullptr, qkv, nullptr, 8192, 3072, 1024, 0, 0);
  vtrans<<<dim3(16, 128), 256, 0, stream>>>(qkv, Vt);
  attn_kernel<<<dim3(16, 128), 256, 0, stream>>>(qkv, Vt, ctx);
  gemm_bt<128><<<dim3(8, 64), 256, 0, stream>>>(ctx, Wproj_b, bproj, x, nullptr, out1, nullptr, 8192, 1024, 1024, 0, 0);
  cvt_f32_bf16<<<2048, 256, 0, stream>>>(W1, W1_b, 4 * 1024 * 1024);
  ln_bf16<<<2048, 256, 0, stream>>>(out1, ln2g, ln2b, h2);
  gemm_bt<64><<<dim3(32, 64), 256, 0, stream>>>(h2, W1_b, b1, nullptr, nullptr, ff1, nullptr, 8192, 4096, 1024, 1, 0);
  cvt_f32_bf16<<<2048, 256, 0, stream>>>(W2, W2_b, 4 * 1024 * 1024);
  gemm_bt<128><<<dim3(8, 64), 256, 0, stream>>>(ff1, W2_b, b2, nullptr, out1, nullptr, out, 8192, 1024, 4096, 1, 1);
}